// Round 7
// baseline (197.430 us; speedup 1.0000x reference)
//
#include <hip/hip_runtime.h>

#pragma clang fp contract(off)

#define NBOX 8192
#define BLK  1024
#define EPT  8
#define NBUCK 2048
#define NB 256
#define IOU_THR 0.1f

typedef unsigned short u16;
typedef unsigned int u32;
typedef unsigned long long u64;

#define SMEM_TOT 162944

__global__ __launch_bounds__(BLK, 4) void nms_kernel(const float* __restrict__ in,
                                                     float* __restrict__ out) {
    __shared__ __align__(16) char smem[SMEM_TOT];
    const int img = blockIdx.x;
    const float* __restrict__ p = in + (size_t)img * 5 * NBOX;
    float* __restrict__ o = out + (size_t)img * 5 * NBOX;
    const int t = threadIdx.x;
    const int lane = t & 63;
    const int wid = t >> 6;

    // persistent LDS
    float4* box   = (float4*)smem;                 // 128 KB: x1,y1,x2,y2 by orig idx
    u16* A        = (u16*)(smem + 131072);         // 16 KB: alive list (orig idx, rank order)
    float4* bx    = (float4*)(smem + 147456);      // 4 KB: staged batch coords (compact)
    u64 (*mat)[4] = (u64(*)[4])(smem + 151552);    // 8 KB: 256x256 suppression bits
    float4* kx    = (float4*)(smem + 151552);      // overlay mat lo: kept coords (area order)
    float4* kxS   = (float4*)(smem + 155648);      // overlay mat hi: kept coords (score order)
    u32* kom      = (u32*)(smem + 159744);         // 1 KB: kept bitmask by orig idx
    int* wcnt     = (int*)(smem + 160768);         // 64 B
    u64* keptQ    = (u64*)(smem + 160832);         // 32 B
    int* S0sh     = (int*)(smem + 160864);
    float* kaS    = (float*)(smem + 160896);       // 1 KB: kept areas (score order)
    u32* pfxA     = (u32*)(smem + 160896);         // alias kaS (output phase only)
    float* kaF    = (float*)(smem + 161920);       // 1 KB: kept areas (area order)
    // sort workspace overlaying box[] (dead after ranking)
    u64* skey  = (u64*)smem;                       // 64 KB
    u32* hist  = (u32*)(smem + 65536);             // 8 KB
    u32* bbase = (u32*)(smem + 73728);             // 8 KB

    // ---- zero output up front (stores drain under the sort) ----
    {
        float4 z; z.x = z.y = z.z = z.w = 0.0f;
        float4* o4 = (float4*)o;
#pragma unroll
        for (int e = 0; e < 10; e++) o4[t + e * BLK] = z;
    }

    // ---- init ----
    for (int i = t; i < NBUCK; i += BLK) hist[i] = 0;
    if (t < 256) kom[t] = 0;
    if (t == 0) *S0sh = 0;
    __syncthreads();

    // ---- sort pass 1: bucket + arrival order ----
    u32 mybkt[EPT], myarr[EPT], mykeyhi[EPT];
#pragma unroll
    for (int e = 0; e < EPT; e++) {
        int j = t + e * BLK;
        float s = p[4 * NBOX + j];
        u32 u = __float_as_uint(s);
        u32 ordb = u ^ (u32)(((int)u >> 31) | (int)0x80000000);
        mykeyhi[e] = ~ordb;                        // ascending == score desc
        int vb = (int)(s * (float)NBUCK);
        vb = vb < 0 ? 0 : (vb > NBUCK - 1 ? NBUCK - 1 : vb);
        mybkt[e] = (u32)(NBUCK - 1 - vb);
        myarr[e] = atomicAdd(&hist[mybkt[e]], 1u);
        u64 bal = __ballot(s > 0.0f);
        if (lane == 0) atomicAdd(S0sh, (int)__popcll(bal));
    }
    __syncthreads();

    // ---- exclusive scan over hist (2 bins/thread) ----
    {
        u32 h0 = hist[2 * t], h1 = hist[2 * t + 1];
        int v = (int)(h0 + h1);
        int x = v;
        for (int d = 1; d < 64; d <<= 1) {
            int y = __shfl_up(x, d, 64);
            if (lane >= d) x += y;
        }
        if (lane == 63) wcnt[wid] = x;
        __syncthreads();
        int wb = 0;
        for (int i = 0; i < wid; i++) wb += wcnt[i];
        int excl = wb + x - v;
        bbase[2 * t] = (u32)excl;
        bbase[2 * t + 1] = (u32)excl + h0;
    }
    __syncthreads();

    // ---- scatter keys ----
#pragma unroll
    for (int e = 0; e < EPT; e++) {
        u32 pos = bbase[mybkt[e]] + myarr[e];
        skey[pos] = ((u64)mykeyhi[e] << 32) | (u32)(t + e * BLK);
    }
    __syncthreads();

    // ---- rank within bucket -> A[rank] = orig idx ----
#pragma unroll
    for (int e = 0; e < EPT; e++) {
        u32 b = mybkt[e];
        u32 lo = bbase[b], hi2 = lo + hist[b];
        u64 me = ((u64)mykeyhi[e] << 32) | (u32)(t + e * BLK);
        u32 r = lo;
        for (u32 q = lo; q < hi2; q++) r += (skey[q] < me) ? 1u : 0u;
        A[r] = (u16)(t + e * BLK);
    }
    __syncthreads();   // sort workspace dead after this
    int S = *S0sh;

    // ---- fill box[] (coalesced row reads, b128 LDS writes) ----
#pragma unroll
    for (int e = 0; e < EPT; e++) {
        int j = t + e * BLK;
        float cx = p[j], cy = p[NBOX + j];
        float w_ = p[2 * NBOX + j], h_ = p[3 * NBOX + j];
        box[j] = make_float4(cx - w_ * 0.5f, cy - h_ * 0.5f,
                             cx + w_ * 0.5f, cy + h_ * 0.5f);
    }
    __syncthreads();

    // ---- stage initial batch coords ----
    if (t < NB) bx[t] = box[A[t]];
    __syncthreads();

    // ---- batched greedy loop ----
    while (S > 0) {
        int nb = S < NB ? S : NB;

        // (E) suppression bit-matrix: row i = t>>2, word ws = t&3 (64 tests each)
        // column start rotated by 2*ws so the wave's 4 b128 addresses hit
        // disjoint bank quads (kills the 4-way conflict)
        {
            int i = t >> 2, ws = t & 3;
            if (i < nb) {
                float4 bi = bx[i];
                float ari = (bi.z - bi.x) * (bi.w - bi.y);
                u64 bits = 0;
                int c0 = ws * 64;
#pragma unroll 4
                for (int cc = 0; cc < 64; cc++) {
                    int ccr = (cc + 2 * ws) & 63;
                    int c = c0 + ccr;
                    if (c < nb && c != i) {
                        float4 bc = bx[c];
                        float arc = (bc.z - bc.x) * (bc.w - bc.y);
                        float iw = fminf(bi.z, bc.z) - fmaxf(bi.x, bc.x);
                        float ih = fminf(bi.w, bc.w) - fmaxf(bi.y, bc.y);
                        if (iw > 0.0f && ih > 0.0f) {
                            float inter = iw * ih;
                            float uni = ari + arc - inter;
                            if (inter / (uni + 1e-8f) >= IOU_THR) bits |= (1ull << ccr);
                        }
                    }
                }
                mat[i][ws] = bits;
            }
        }
        __syncthreads();  // B1

        // (G) wave 0: closure resolve (exact greedy on batch)
        if (wid == 0) {
            u64 r0[4], r1[4], r2[4], r3[4];
#pragma unroll
            for (int wq = 0; wq < 4; wq++) {
                r0[wq] = mat[lane][wq];
                r1[wq] = mat[64 + lane][wq];
                r2[wq] = mat[128 + lane][wq];
                r3[wq] = mat[192 + lane][wq];
            }
            u64 A0, A1, A2, A3;
            {
                int n0 = nb;       A0 = n0 <= 0 ? 0ull : (n0 >= 64 ? ~0ull : ((1ull << n0) - 1ull));
                int n1 = nb - 64;  A1 = n1 <= 0 ? 0ull : (n1 >= 64 ? ~0ull : ((1ull << n1) - 1ull));
                int n2 = nb - 128; A2 = n2 <= 0 ? 0ull : (n2 >= 64 ? ~0ull : ((1ull << n2) - 1ull));
                int n3 = nb - 192; A3 = n3 <= 0 ? 0ull : (n3 >= 64 ? ~0ull : ((1ull << n3) - 1ull));
            }
            u64 K0 = 0, K1 = 0, K2 = 0, K3 = 0;
            u64 lm = (1ull << lane) - 1ull;
            while (A0 | A1 | A2 | A3) {
                bool c0b = ((A0 >> lane) & 1) && !(r0[0] & A0 & lm);
                bool c1b = ((A1 >> lane) & 1) && !((r1[0] & A0) | (r1[1] & A1 & lm));
                bool c2b = ((A2 >> lane) & 1) && !((r2[0] & A0) | (r2[1] & A1) | (r2[2] & A2 & lm));
                bool c3b = ((A3 >> lane) & 1) && !((r3[0] & A0) | (r3[1] & A1) | (r3[2] & A2) | (r3[3] & A3 & lm));
                u64 C0 = __ballot(c0b), C1 = __ballot(c1b), C2 = __ballot(c2b), C3 = __ballot(c3b);
                K0 |= C0; K1 |= C1; K2 |= C2; K3 |= C3;
                A0 &= ~C0; A1 &= ~C1; A2 &= ~C2; A3 &= ~C3;
                bool s0b = ((A0 >> lane) & 1) && ((r0[0] & C0) | (r0[1] & C1) | (r0[2] & C2) | (r0[3] & C3));
                bool s1b = ((A1 >> lane) & 1) && ((r1[0] & C0) | (r1[1] & C1) | (r1[2] & C2) | (r1[3] & C3));
                bool s2b = ((A2 >> lane) & 1) && ((r2[0] & C0) | (r2[1] & C1) | (r2[2] & C2) | (r2[3] & C3));
                bool s3b = ((A3 >> lane) & 1) && ((r3[0] & C0) | (r3[1] & C1) | (r3[2] & C2) | (r3[3] & C3));
                A0 &= ~__ballot(s0b); A1 &= ~__ballot(s1b); A2 &= ~__ballot(s2b); A3 &= ~__ballot(s3b);
            }
            if (lane < 4) keptQ[lane] = lane == 0 ? K0 : lane == 1 ? K1 : lane == 2 ? K2 : K3;
        }
        __syncthreads();  // B2

        // (I) apply batch decisions: kom bits + score-order compact into kxS/kaS
        u64 kq0 = keptQ[0], kq1 = keptQ[1], kq2 = keptQ[2], kq3 = keptQ[3];
        int nk = (int)(__popcll(kq0) + __popcll(kq1) + __popcll(kq2) + __popcll(kq3));
        if (t < nb) {
            int wq = t >> 6;
            u64 kq = wq == 0 ? kq0 : wq == 1 ? kq1 : wq == 2 ? kq2 : kq3;
            if ((kq >> (t & 63)) & 1) {
                int j = (int)A[t];
                atomicOr(&kom[j >> 5], 1u << (j & 31));
                int pk = 0;
                if (wq > 0) pk += (int)__popcll(kq0);
                if (wq > 1) pk += (int)__popcll(kq1);
                if (wq > 2) pk += (int)__popcll(kq2);
                pk += (int)__popcll(kq & ((1ull << (t & 63)) - 1ull));
                float4 b = bx[t];
                kxS[pk] = b;
                kaS[pk] = (b.z - b.x) * (b.w - b.y);
            }
        }
        // load tail entries (reads A/box; compaction writes A only after B4)
        int tailN = S - nb;
        int C = (tailN + BLK - 1) / BLK;   // 0..8
        int st = nb + t * C;
        int en = st + C; if (en > S) en = S;
        float4 eb[EPT]; float ea[EPT]; u16 ei[EPT];
        u32 am = 0;
#pragma unroll
        for (int e = 0; e < EPT; e++) {
            int pos = st + e;
            if (e < C && pos < en) {
                u16 j = A[pos];
                ei[e] = j;
                float4 b = box[j];
                eb[e] = b;
                ea[e] = (b.z - b.x) * (b.w - b.y);
                am |= (1u << e);
            }
        }
        __syncthreads();  // B2b: kxS/kaS visible

        // (I2) reorder kept by area DESC (order-free existential test -> allowed)
        if (t < nk) {
            float aq = kaS[t];
            float4 bq = kxS[t];
            int rk = 0;
            for (int c = 0; c < nk; c++) {
                float ac = kaS[c];
                rk += (ac > aq) || (ac == aq && c < t) ? 1 : 0;
            }
            kx[rk] = bq;
            kaF[rk] = aq;
        }
        __syncthreads();  // B3: kx/kaF visible

        // (K) tail suppression: area-ordered kept walk, early break
        if (am) {
            for (int c = 0; c < nk; c++) {
                float4 cb = kx[c];
                float arc = kaF[c];
#pragma unroll
                for (int e = 0; e < EPT; e++) {
                    if (am & (1u << e)) {
                        float iw = fminf(eb[e].z, cb.z) - fmaxf(eb[e].x, cb.x);
                        float ih = fminf(eb[e].w, cb.w) - fmaxf(eb[e].y, cb.y);
                        if (iw > 0.0f && ih > 0.0f) {
                            float inter = iw * ih;
                            float uni = ea[e] + arc - inter;
                            if (inter / (uni + 1e-8f) >= IOU_THR) am &= ~(1u << e);
                        }
                    }
                }
                if (!am) break;
            }
        }

        // compaction: order-preserving block scan; scatter A (and bx for new batch)
        {
            int cnt = __popc(am);
            int x = cnt;
            for (int d = 1; d < 64; d <<= 1) {
                int y = __shfl_up(x, d, 64);
                if (lane >= d) x += y;
            }
            if (lane == 63) wcnt[wid] = x;
            __syncthreads();  // B4
            int wb = 0, tot = 0;
            for (int i = 0; i < BLK / 64; i++) {
                int v = wcnt[i];
                if (i < wid) wb += v;
                tot += v;
            }
            int off = wb + x - cnt;
#pragma unroll
            for (int e = 0; e < EPT; e++) {
                if (am & (1u << e)) {
                    A[off] = ei[e];
                    if (off < NB) bx[off] = eb[e];
                    off++;
                }
            }
            __syncthreads();  // B5
            S = tot;
        }
    }
    __syncthreads();

    // ---- output: prefix over kom, scatter kept columns (out pre-zeroed at entry) ----
    {
        u32 w = (t < 256) ? kom[t] : 0u;
        int c = __popc(w);
        int x = c;
        for (int d = 1; d < 64; d <<= 1) {
            int y = __shfl_up(x, d, 64);
            if (lane >= d) x += y;
        }
        if (lane == 63) wcnt[wid] = x;
        __syncthreads();
        int wb = 0;
        for (int i = 0; i < wid; i++) wb += wcnt[i];
        if (t < 256) pfxA[t] = (u32)(wb + x - c);
    }
    __syncthreads();
    for (int j = t; j < NBOX; j += BLK) {
        u32 km = kom[j >> 5];
        if ((km >> (j & 31)) & 1u) {
            int pos = (int)(pfxA[j >> 5] + (u32)__popc(km & ((1u << (j & 31)) - 1u)));
            o[0 * NBOX + pos] = p[0 * NBOX + j];
            o[1 * NBOX + pos] = p[1 * NBOX + j];
            o[2 * NBOX + pos] = p[2 * NBOX + j];
            o[3 * NBOX + pos] = p[3 * NBOX + j];
            o[4 * NBOX + pos] = p[4 * NBOX + j];
        }
    }
}

extern "C" void kernel_launch(void* const* d_in, const int* in_sizes, int n_in,
                              void* d_out, int out_size, void* d_ws, size_t ws_size,
                              hipStream_t stream) {
    const float* in = (const float*)d_in[0];
    float* out = (float*)d_out;
    int B = in_sizes[0] / (5 * NBOX);
    hipLaunchKernelGGL(nms_kernel, dim3(B), dim3(BLK), 0, stream, in, out);
}

// Round 8
// 162.152 us; speedup vs baseline: 1.2176x; 1.2176x over previous
//
#include <hip/hip_runtime.h>

#pragma clang fp contract(off)

#define NBOX 8192
#define BLK  1024
#define EPT  8
#define NBUCK 2048
#define NB 256
#define IOU_THR 0.1f

typedef unsigned short u16;
typedef unsigned int u32;
typedef unsigned long long u64;

// Exact division-free IoU threshold test:
// round_f32(inter/u) >= 0.1f  <=>  inter/u > m, m = midpoint(pred(0.1f), 0.1f).
// (tie q==m rounds-to-even to pred(0.1f) < 0.1f, hence strict >)
// m = 0x1.999999p-4 exactly; m*(double)u has <=49 mantissa bits -> exact.
#define MND 0x1.999999p-4

#define SMEM_TOT 160896

__global__ __launch_bounds__(BLK, 4) void nms_kernel(const float* __restrict__ in,
                                                     float* __restrict__ out) {
    __shared__ __align__(16) char smem[SMEM_TOT];
    const int img = blockIdx.x;
    const float* __restrict__ p = in + (size_t)img * 5 * NBOX;
    float* __restrict__ o = out + (size_t)img * 5 * NBOX;
    const int t = threadIdx.x;
    const int lane = t & 63;
    const int wid = t >> 6;

    // persistent LDS
    float4* box   = (float4*)smem;                 // 128 KB: x1,y1,x2,y2 by orig idx
    u16* A        = (u16*)(smem + 131072);         // 16 KB: alive list (orig idx, rank order)
    float4* bx    = (float4*)(smem + 147456);      // 4 KB: staged batch coords (compact)
    u64 (*mat)[4] = (u64(*)[4])(smem + 151552);    // 8 KB: 256x256 suppression bits
    float4* kx    = (float4*)(smem + 151552);      // overlay mat lo: kept coords
    u32* pfxA     = (u32*)(smem + 155648);         // overlay mat hi (post-loop)
    u32* kom      = (u32*)(smem + 159744);         // 1 KB: kept bitmask by orig idx
    int* wcnt     = (int*)(smem + 160768);         // 64 B
    u64* keptQ    = (u64*)(smem + 160832);         // 32 B
    int* S0sh     = (int*)(smem + 160864);
    // sort workspace overlaying box[] (dead after ranking)
    u64* skey  = (u64*)smem;                       // 64 KB
    u32* hist  = (u32*)(smem + 65536);             // 8 KB
    u32* bbase = (u32*)(smem + 73728);             // 8 KB

    // ---- init ----
    for (int i = t; i < NBUCK; i += BLK) hist[i] = 0;
    if (t < 256) kom[t] = 0;
    if (t == 0) *S0sh = 0;
    __syncthreads();

    // ---- sort pass 1: bucket + arrival order ----
    u32 mybkt[EPT], myarr[EPT], mykeyhi[EPT];
#pragma unroll
    for (int e = 0; e < EPT; e++) {
        int j = t + e * BLK;
        float s = p[4 * NBOX + j];
        u32 u = __float_as_uint(s);
        u32 ordb = u ^ (u32)(((int)u >> 31) | (int)0x80000000);
        mykeyhi[e] = ~ordb;                        // ascending == score desc
        int vb = (int)(s * (float)NBUCK);
        vb = vb < 0 ? 0 : (vb > NBUCK - 1 ? NBUCK - 1 : vb);
        mybkt[e] = (u32)(NBUCK - 1 - vb);
        myarr[e] = atomicAdd(&hist[mybkt[e]], 1u);
        u64 bal = __ballot(s > 0.0f);
        if (lane == 0) atomicAdd(S0sh, (int)__popcll(bal));
    }
    __syncthreads();

    // ---- exclusive scan over hist (2 bins/thread) ----
    {
        u32 h0 = hist[2 * t], h1 = hist[2 * t + 1];
        int v = (int)(h0 + h1);
        int x = v;
        for (int d = 1; d < 64; d <<= 1) {
            int y = __shfl_up(x, d, 64);
            if (lane >= d) x += y;
        }
        if (lane == 63) wcnt[wid] = x;
        __syncthreads();
        int wb = 0;
        for (int i = 0; i < wid; i++) wb += wcnt[i];
        int excl = wb + x - v;
        bbase[2 * t] = (u32)excl;
        bbase[2 * t + 1] = (u32)excl + h0;
    }
    __syncthreads();

    // ---- scatter keys ----
#pragma unroll
    for (int e = 0; e < EPT; e++) {
        u32 pos = bbase[mybkt[e]] + myarr[e];
        skey[pos] = ((u64)mykeyhi[e] << 32) | (u32)(t + e * BLK);
    }
    __syncthreads();

    // ---- rank within bucket -> A[rank] = orig idx ----
#pragma unroll
    for (int e = 0; e < EPT; e++) {
        u32 b = mybkt[e];
        u32 lo = bbase[b], hi2 = lo + hist[b];
        u64 me = ((u64)mykeyhi[e] << 32) | (u32)(t + e * BLK);
        u32 r = lo;
        for (u32 q = lo; q < hi2; q++) r += (skey[q] < me) ? 1u : 0u;
        A[r] = (u16)(t + e * BLK);
    }
    __syncthreads();   // sort workspace dead after this
    int S = *S0sh;

    // ---- fill box[] (coalesced row reads, b128 LDS writes) ----
#pragma unroll
    for (int e = 0; e < EPT; e++) {
        int j = t + e * BLK;
        float cx = p[j], cy = p[NBOX + j];
        float w_ = p[2 * NBOX + j], h_ = p[3 * NBOX + j];
        box[j] = make_float4(cx - w_ * 0.5f, cy - h_ * 0.5f,
                             cx + w_ * 0.5f, cy + h_ * 0.5f);
    }
    __syncthreads();

    // ---- stage initial batch coords ----
    if (t < NB) bx[t] = box[A[t]];
    __syncthreads();

    // ---- batched greedy loop ----
    while (S > 0) {
        int nb = S < NB ? S : NB;

        // (E) suppression bit-matrix: row i = t>>2, word ws = t&3
        // branchless exact test, no divide, no divergence
        {
            int i = t >> 2, ws = t & 3;
            if (i < nb) {
                float4 bi = bx[i];
                float ari = (bi.z - bi.x) * (bi.w - bi.y);
                u64 bits = 0;
                int c0 = ws * 64;
                int cmax = nb - c0; if (cmax > 64) cmax = 64;
                for (int cc = 0; cc < cmax; cc++) {
                    float4 bc = bx[c0 + cc];
                    float arc = (bc.z - bc.x) * (bc.w - bc.y);
                    float iw = fmaxf(fminf(bi.z, bc.z) - fmaxf(bi.x, bc.x), 0.0f);
                    float ih = fmaxf(fminf(bi.w, bc.w) - fmaxf(bi.y, bc.y), 0.0f);
                    float inter = iw * ih;
                    float t1 = ari + arc;
                    float t2 = t1 - inter;
                    float u  = t2 + 1e-8f;
                    if ((double)inter > MND * (double)u) bits |= (1ull << cc);
                }
                if (i >= c0 && i < c0 + 64) bits &= ~(1ull << (i - c0));
                mat[i][ws] = bits;
            }
        }
        __syncthreads();  // B1

        // (G) wave 0: closure resolve (exact greedy on batch)
        if (wid == 0) {
            u64 r0[4], r1[4], r2[4], r3[4];
#pragma unroll
            for (int wq = 0; wq < 4; wq++) {
                r0[wq] = mat[lane][wq];
                r1[wq] = mat[64 + lane][wq];
                r2[wq] = mat[128 + lane][wq];
                r3[wq] = mat[192 + lane][wq];
            }
            u64 A0, A1, A2, A3;
            {
                int n0 = nb;       A0 = n0 <= 0 ? 0ull : (n0 >= 64 ? ~0ull : ((1ull << n0) - 1ull));
                int n1 = nb - 64;  A1 = n1 <= 0 ? 0ull : (n1 >= 64 ? ~0ull : ((1ull << n1) - 1ull));
                int n2 = nb - 128; A2 = n2 <= 0 ? 0ull : (n2 >= 64 ? ~0ull : ((1ull << n2) - 1ull));
                int n3 = nb - 192; A3 = n3 <= 0 ? 0ull : (n3 >= 64 ? ~0ull : ((1ull << n3) - 1ull));
            }
            u64 K0 = 0, K1 = 0, K2 = 0, K3 = 0;
            u64 lm = (1ull << lane) - 1ull;
            while (A0 | A1 | A2 | A3) {
                bool c0b = ((A0 >> lane) & 1) && !(r0[0] & A0 & lm);
                bool c1b = ((A1 >> lane) & 1) && !((r1[0] & A0) | (r1[1] & A1 & lm));
                bool c2b = ((A2 >> lane) & 1) && !((r2[0] & A0) | (r2[1] & A1) | (r2[2] & A2 & lm));
                bool c3b = ((A3 >> lane) & 1) && !((r3[0] & A0) | (r3[1] & A1) | (r3[2] & A2) | (r3[3] & A3 & lm));
                u64 C0 = __ballot(c0b), C1 = __ballot(c1b), C2 = __ballot(c2b), C3 = __ballot(c3b);
                K0 |= C0; K1 |= C1; K2 |= C2; K3 |= C3;
                A0 &= ~C0; A1 &= ~C1; A2 &= ~C2; A3 &= ~C3;
                bool s0b = ((A0 >> lane) & 1) && ((r0[0] & C0) | (r0[1] & C1) | (r0[2] & C2) | (r0[3] & C3));
                bool s1b = ((A1 >> lane) & 1) && ((r1[0] & C0) | (r1[1] & C1) | (r1[2] & C2) | (r1[3] & C3));
                bool s2b = ((A2 >> lane) & 1) && ((r2[0] & C0) | (r2[1] & C1) | (r2[2] & C2) | (r2[3] & C3));
                bool s3b = ((A3 >> lane) & 1) && ((r3[0] & C0) | (r3[1] & C1) | (r3[2] & C2) | (r3[3] & C3));
                A0 &= ~__ballot(s0b); A1 &= ~__ballot(s1b); A2 &= ~__ballot(s2b); A3 &= ~__ballot(s3b);
            }
            if (lane < 4) keptQ[lane] = lane == 0 ? K0 : lane == 1 ? K1 : lane == 2 ? K2 : K3;
        }
        __syncthreads();  // B2

        // (I) apply batch decisions (compact kept coords into kx), load tail entries
        u64 kq0 = keptQ[0], kq1 = keptQ[1], kq2 = keptQ[2], kq3 = keptQ[3];
        int nk = (int)(__popcll(kq0) + __popcll(kq1) + __popcll(kq2) + __popcll(kq3));
        if (t < nb) {
            int wq = t >> 6;
            u64 kq = wq == 0 ? kq0 : wq == 1 ? kq1 : wq == 2 ? kq2 : kq3;
            if ((kq >> (t & 63)) & 1) {
                int j = (int)A[t];
                atomicOr(&kom[j >> 5], 1u << (j & 31));
                int pk = 0;
                if (wq > 0) pk += (int)__popcll(kq0);
                if (wq > 1) pk += (int)__popcll(kq1);
                if (wq > 2) pk += (int)__popcll(kq2);
                pk += (int)__popcll(kq & ((1ull << (t & 63)) - 1ull));
                kx[pk] = bx[t];
            }
        }
        int tailN = S - nb;
        int C = (tailN + BLK - 1) / BLK;   // 0..8
        int st = nb + t * C;
        int en = st + C; if (en > S) en = S;
        float4 eb[EPT]; float ea[EPT]; u16 ei[EPT];
        u32 am = 0;
#pragma unroll
        for (int e = 0; e < EPT; e++) {
            int pos = st + e;
            if (e < C && pos < en) {
                u16 j = A[pos];
                ei[e] = j;
                float4 b = box[j];
                eb[e] = b;
                ea[e] = (b.z - b.x) * (b.w - b.y);
                am |= (1u << e);
            }
        }
        __syncthreads();  // B3: kx visible; all A/bx reads done

        // (K) tail suppression: sequential kx walk, f64-compare instead of div
        if (am) {
            for (int c = 0; c < nk; c++) {
                float4 cb = kx[c];
                float arc = (cb.z - cb.x) * (cb.w - cb.y);
#pragma unroll
                for (int e = 0; e < EPT; e++) {
                    if (am & (1u << e)) {
                        float iw = fminf(eb[e].z, cb.z) - fmaxf(eb[e].x, cb.x);
                        float ih = fminf(eb[e].w, cb.w) - fmaxf(eb[e].y, cb.y);
                        if (iw > 0.0f && ih > 0.0f) {
                            float inter = iw * ih;
                            float t1 = ea[e] + arc;
                            float t2 = t1 - inter;
                            float u  = t2 + 1e-8f;
                            if ((double)inter > MND * (double)u) am &= ~(1u << e);
                        }
                    }
                }
                if (!am) break;
            }
        }

        // compaction: order-preserving block scan; scatter A (and bx for new batch)
        {
            int cnt = __popc(am);
            int x = cnt;
            for (int d = 1; d < 64; d <<= 1) {
                int y = __shfl_up(x, d, 64);
                if (lane >= d) x += y;
            }
            if (lane == 63) wcnt[wid] = x;
            __syncthreads();  // B4
            int wb = 0, tot = 0;
            for (int i = 0; i < BLK / 64; i++) {
                int v = wcnt[i];
                if (i < wid) wb += v;
                tot += v;
            }
            int off = wb + x - cnt;
#pragma unroll
            for (int e = 0; e < EPT; e++) {
                if (am & (1u << e)) {
                    A[off] = ei[e];
                    if (off < NB) bx[off] = eb[e];
                    off++;
                }
            }
            __syncthreads();  // B5
            S = tot;
        }
    }
    __syncthreads();

    // ---- output: zero, prefix over kom, scatter kept columns ----
    {
        float4 z; z.x = z.y = z.z = z.w = 0.0f;
        float4* o4 = (float4*)o;
        for (int i = t; i < 5 * NBOX / 4; i += BLK) o4[i] = z;
    }
    {
        u32 w = (t < 256) ? kom[t] : 0u;
        int c = __popc(w);
        int x = c;
        for (int d = 1; d < 64; d <<= 1) {
            int y = __shfl_up(x, d, 64);
            if (lane >= d) x += y;
        }
        if (lane == 63) wcnt[wid] = x;
        __syncthreads();
        int wb = 0;
        for (int i = 0; i < wid; i++) wb += wcnt[i];
        if (t < 256) pfxA[t] = (u32)(wb + x - c);
    }
    __syncthreads();
    for (int j = t; j < NBOX; j += BLK) {
        u32 km = kom[j >> 5];
        if ((km >> (j & 31)) & 1u) {
            int pos = (int)(pfxA[j >> 5] + (u32)__popc(km & ((1u << (j & 31)) - 1u)));
            o[0 * NBOX + pos] = p[0 * NBOX + j];
            o[1 * NBOX + pos] = p[1 * NBOX + j];
            o[2 * NBOX + pos] = p[2 * NBOX + j];
            o[3 * NBOX + pos] = p[3 * NBOX + j];
            o[4 * NBOX + pos] = p[4 * NBOX + j];
        }
    }
}

extern "C" void kernel_launch(void* const* d_in, const int* in_sizes, int n_in,
                              void* d_out, int out_size, void* d_ws, size_t ws_size,
                              hipStream_t stream) {
    const float* in = (const float*)d_in[0];
    float* out = (float*)d_out;
    int B = in_sizes[0] / (5 * NBOX);
    hipLaunchKernelGGL(nms_kernel, dim3(B), dim3(BLK), 0, stream, in, out);
}